// Round 15
// baseline (705.881 us; speedup 1.0000x reference)
//
#include <hip/hip_runtime.h>

#define HID 128
#define BSHIFT 10            // 1024 dst-nodes per bucket
#define BCAP 20480           // bucket capacity (mean 16.3K, sigma ~127 -> 32 sigma)

typedef _Float16 half8 __attribute__((ext_vector_type(8)));
typedef _Float16 half4v __attribute__((ext_vector_type(4)));
typedef float f32x4 __attribute__((ext_vector_type(4)));

__device__ __forceinline__ half8 cvt8(f32x4 f0, f32x4 f1) {
  half8 h;
  h[0] = (_Float16)f0[0]; h[1] = (_Float16)f0[1];
  h[2] = (_Float16)f0[2]; h[3] = (_Float16)f0[3];
  h[4] = (_Float16)f1[0]; h[5] = (_Float16)f1[1];
  h[6] = (_Float16)f1[2]; h[7] = (_Float16)f1[3];
  return h;
}

// ---------------- graph build: two-pass binned scatter ----------------

__global__ __launch_bounds__(256) void zero_i32(int* __restrict__ p, int n) {
  int i = blockIdx.x * 256 + threadIdx.x;
  if (i < n) p[i] = 0;
}

__global__ __launch_bounds__(256) void bin_edges(const int* __restrict__ ei,
                                                 int* __restrict__ gcur,
                                                 int2* __restrict__ buf,
                                                 int E, int NB) {
  __shared__ int bcnt[128];
  __shared__ int bbase[128];
  const int tid = threadIdx.x;

  for (int chunk = blockIdx.x * 2048; chunk < E; chunk += gridDim.x * 2048) {
    if (tid < NB) bcnt[tid] = 0;
    __syncthreads();
    int s[8], d[8], slot[8], b[8];
#pragma unroll
    for (int j = 0; j < 8; ++j) {
      int e = chunk + tid + j * 256;
      if (e < E) {
        s[j] = ei[e];
        d[j] = ei[E + e];
        b[j] = d[j] >> BSHIFT;
        slot[j] = atomicAdd(&bcnt[b[j]], 1);
      } else {
        b[j] = -1;
      }
    }
    __syncthreads();
    if (tid < NB && bcnt[tid] > 0) bbase[tid] = atomicAdd(&gcur[tid], bcnt[tid]);
    __syncthreads();
#pragma unroll
    for (int j = 0; j < 8; ++j) {
      if (b[j] >= 0) {
        int pos = bbase[b[j]] + slot[j];
        if (pos < BCAP) buf[(size_t)b[j] * BCAP + pos] = make_int2(s[j], d[j]);
      }
    }
    __syncthreads();
  }
}

__global__ __launch_bounds__(256) void scatter_pad(const int2* __restrict__ buf,
                                                   const int* __restrict__ gcur,
                                                   int* __restrict__ colpad,
                                                   int* __restrict__ cnt,
                                                   float* __restrict__ dinv, int N) {
  __shared__ int lcnt[1 << BSHIFT];
  const int b = blockIdx.x;
  const int base = b << BSHIFT;
  const int tid = threadIdx.x;
  for (int i = tid; i < (1 << BSHIFT); i += 256) lcnt[i] = 0;
  __syncthreads();

  int ne = gcur[b];
  if (ne > BCAP) ne = BCAP;
  const int2* __restrict__ bb = buf + (size_t)b * BCAP;
  for (int i = tid; i < ne; i += 256) {
    int2 p = bb[i];
    int pos = atomicAdd(&lcnt[p.y - base], 1);
    if (pos < 64) colpad[(size_t)p.y * 64 + pos] = p.x;
  }
  __syncthreads();
  for (int i = tid; i < (1 << BSHIFT); i += 256) {
    int n = base + i;
    if (n < N) {
      int c = lcnt[i];
      cnt[n] = c;
      dinv[n] = rsqrtf((float)(c + 1));
    }
  }
}

// ---------------- weight convert fp32 -> f16 ----------------

__global__ __launch_bounds__(256) void cvt_w2(const float* __restrict__ a, int na,
                                              const float* __restrict__ b, int nb,
                                              _Float16* __restrict__ oa,
                                              _Float16* __restrict__ ob) {
  int i = blockIdx.x * 256 + threadIdx.x;
  if (i < na) oa[i] = (_Float16)a[i];
  else if (i < na + nb) ob[i - na] = (_Float16)b[i - na];
}

// ---------------- streaming MFMA GEMM ("cvt_x-ified") ----------------
// out[N][128] = A[N][K] @ W[128][K]^T.  W staged to LDS ONCE (only barrier),
// then each wave independently grid-strides over 16-row tiles: A global->regs
// via 4-slot consume-then-refill pipeline, B from LDS (XOR-swizzled), no
// main-loop barriers.  High occupancy is the latency hider (cvt_x lesson):
// K=512: 1024 thr, 128KB LDS -> 16 waves/CU; K=128: 512 thr, 32KB -> 100% occ.

template <int K, bool CONVA, int NTHR>
__global__ __launch_bounds__(NTHR) void gemm_stream(const void* __restrict__ Av,
                                                    const _Float16* __restrict__ Wh,
                                                    const float* __restrict__ bias,
                                                    const float* __restrict__ rowscale,
                                                    _Float16* __restrict__ out,
                                                    int N, int do_relu) {
  constexpr int KS = K / 32;                      // MFMA k-steps
  constexpr int NW = NTHR / 64;                   // waves per block
  __shared__ __align__(16) char Ws[128 * K * 2];  // K=512: 128KB; K=128: 32KB

  const int tid = threadIdx.x;
  const int lane = tid & 63;
  const int wave = tid >> 6;
  const int rsel = lane & 15;  // A row-within-16 / W-row selector / C col
  const int q = lane >> 4;     // k-quarter

  const float* Af = (const float*)Av;
  const _Float16* Ah = (const _Float16*)Av;

  // ---- stage W into LDS (once), swizzled: chunk j -> j ^ (c&7) ----
  constexpr int NCH = 128 * (K / 8);
#pragma unroll
  for (int i = 0; i < NCH / NTHR; ++i) {
    int ch = tid + i * NTHR;
    int c = ch / (K / 8);
    int j = ch % (K / 8);
    *(half8*)(Ws + (size_t)c * (K * 2) + (size_t)(j ^ (c & 7)) * 16) =
        *(const half8*)(Wh + (size_t)c * K + j * 8);
  }
  __syncthreads();

  const int ntiles = (N + 15) / 16;
  for (int t = blockIdx.x * NW + wave; t < ntiles; t += gridDim.x * NW) {
    const int row0 = t * 16;
    int gr = row0 + rsel;
    if (gr >= N) gr = N - 1;  // clamp; stores masked in epilogue
    const char* ap;
    if constexpr (CONVA) ap = (const char*)(Af + (size_t)gr * K + q * 8);
    else                 ap = (const char*)(Ah + (size_t)gr * K + q * 8);

    f32x4 acc[8];
#pragma unroll
    for (int ni = 0; ni < 8; ++ni) acc[ni] = (f32x4){0.f, 0.f, 0.f, 0.f};

    f32x4 fb[4][2];  // [slot][half]  (CONVA)
    half8 hb[4];     // [slot]        (f16)

#define LOADK(SLOT, KSI)                                                     \
  do {                                                                       \
    if constexpr (CONVA) {                                                   \
      fb[SLOT][0] = *(const f32x4*)(ap + (KSI) * 128);                       \
      fb[SLOT][1] = *(const f32x4*)(ap + (KSI) * 128 + 16);                  \
    } else {                                                                 \
      hb[SLOT] = *(const half8*)(ap + (KSI) * 64);                           \
    }                                                                        \
  } while (0)

#define MMAK(SLOT, KSI)                                                      \
  do {                                                                       \
    half8 av;                                                                \
    if constexpr (CONVA) av = cvt8(fb[SLOT][0], fb[SLOT][1]);                \
    else                 av = hb[SLOT];                                      \
    _Pragma("unroll")                                                        \
    for (int ni = 0; ni < 8; ++ni) {                                         \
      int c = ni * 16 + rsel;                                                \
      half8 bv = *(const half8*)(Ws + (size_t)c * (K * 2) +                  \
                                 (size_t)((((KSI) * 4 + q)) ^ (c & 7)) * 16);\
      acc[ni] =                                                              \
          __builtin_amdgcn_mfma_f32_16x16x32_f16(av, bv, acc[ni], 0, 0, 0);  \
    }                                                                        \
  } while (0)

    LOADK(0, 0);
    LOADK(1, 1);
    LOADK(2, 2);
    LOADK(3, 3);
#pragma unroll
    for (int ks = 0; ks < KS; ++ks) {
      MMAK(ks & 3, ks);                              // consume slot (holds ks)
      if (ks + 4 < KS) LOADK((ks + 4) & 3, ks + 4);  // THEN refill for ks+4
    }
#undef LOADK
#undef MMAK

    // epilogue: row = row0 + q*4 + j, col = ni*16 + rsel
    const int rsub = q * 4;
#pragma unroll
    for (int j = 0; j < 4; ++j) {
      int grow = row0 + rsub + j;
      if (grow < N) {
        float rs = rowscale ? rowscale[grow] : 1.0f;
#pragma unroll
        for (int ni = 0; ni < 8; ++ni) {
          int c = ni * 16 + rsel;
          float v = acc[ni][j] * rs;
          if (bias) v += bias[c];
          if (do_relu) v = fmaxf(v, 0.f);
          out[(size_t)grow * HID + c] = (_Float16)v;
        }
      }
    }
  }
}

// ---------------- sparse aggregation: 4 rows per wave-instruction ----------------

__global__ __launch_bounds__(256) void agg_pad(const _Float16* __restrict__ g,
                                               const int* __restrict__ cnt,
                                               const int* __restrict__ colpad,
                                               const float* __restrict__ dinv,
                                               const float* __restrict__ bias,
                                               _Float16* __restrict__ out, int N) {
  int node = blockIdx.x * 4 + (threadIdx.x >> 6);
  if (node >= N) return;
  const int lane = threadIdx.x & 63;
  const int es = lane >> 4;   // edge slot 0..3
  const int ch = lane & 15;   // 16-byte chunk 0..15
  const int deg = cnt[node];
  const int* __restrict__ row = colpad + (size_t)node * 64;

  float acc[8] = {0.f, 0.f, 0.f, 0.f, 0.f, 0.f, 0.f, 0.f};
  int e0 = 0;
  for (; e0 + 16 <= deg; e0 += 16) {
    int i0 = row[e0 + es];
    int i1 = row[e0 + 4 + es];
    int i2 = row[e0 + 8 + es];
    int i3 = row[e0 + 12 + es];
    half8 v0 = *(const half8*)(g + (size_t)i0 * HID + ch * 8);
    half8 v1 = *(const half8*)(g + (size_t)i1 * HID + ch * 8);
    half8 v2 = *(const half8*)(g + (size_t)i2 * HID + ch * 8);
    half8 v3 = *(const half8*)(g + (size_t)i3 * HID + ch * 8);
#pragma unroll
    for (int j = 0; j < 8; ++j)
      acc[j] += ((float)v0[j] + (float)v1[j]) + ((float)v2[j] + (float)v3[j]);
  }
  for (; e0 + 4 <= deg; e0 += 4) {
    int i0 = row[e0 + es];
    half8 v0 = *(const half8*)(g + (size_t)i0 * HID + ch * 8);
#pragma unroll
    for (int j = 0; j < 8; ++j) acc[j] += (float)v0[j];
  }
  const int rem = deg - e0;   // 0..3
  float selfw = 1.0f;
  if (rem > 0) {
    int i0 = (es < rem) ? row[e0 + es] : node;  // pad slots gather the self row
    half8 v0 = *(const half8*)(g + (size_t)i0 * HID + ch * 8);
#pragma unroll
    for (int j = 0; j < 8; ++j) acc[j] += (float)v0[j];
    selfw = 1.0f - (float)(4 - rem);  // compensate the (4-rem) extra self rows
  }

#pragma unroll
  for (int j = 0; j < 8; ++j) {
    acc[j] += __shfl_xor(acc[j], 16, 64);
    acc[j] += __shfl_xor(acc[j], 32, 64);
  }

  if (lane < 16) {
    half8 sv = *(const half8*)(g + (size_t)node * HID + ch * 8);
    const float di = dinv[node];
    half8 o;
#pragma unroll
    for (int j = 0; j < 8; ++j) {
      float v = di * (acc[j] + selfw * (float)sv[j]) + bias[ch * 8 + j];
      o[j] = (_Float16)fmaxf(v, 0.f);
    }
    *(half8*)(out + (size_t)node * HID + ch * 8) = o;
  }
}

// ---------------- final GEMM (MFMA): logits[N][40] = h[N][128] @ Wl[40][128]^T + bl ----------------

__global__ __launch_bounds__(256) void gemm40_mfma(const _Float16* __restrict__ h,
                                                   const float* __restrict__ Wl,
                                                   const float* __restrict__ bl,
                                                   float* __restrict__ out, int N) {
  __shared__ __align__(16) _Float16 wlds[48][136];

  const int tid = threadIdx.x;
  const int lane = tid & 63;
  const int wave = tid >> 6;
  const int row0 = blockIdx.x * 128;

#pragma unroll
  for (int i = 0; i < 6; ++i) {
    int idx4 = tid + i * 256;
    int c = idx4 >> 5;
    int ko = (idx4 & 31) * 4;
    float4 v = make_float4(0.f, 0.f, 0.f, 0.f);
    if (c < 40) v = *(const float4*)(Wl + (size_t)c * HID + ko);
    half4v hv;
    hv[0] = (_Float16)v.x; hv[1] = (_Float16)v.y;
    hv[2] = (_Float16)v.z; hv[3] = (_Float16)v.w;
    *(half4v*)&wlds[c][ko] = hv;
  }
  __syncthreads();

  f32x4 acc[2][3] = {};
  const int arow_in = lane & 15;
  const int kq = lane >> 4;

#pragma unroll
  for (int ks = 0; ks < 4; ++ks) {
    half8 a[2], b[3];
#pragma unroll
    for (int mi = 0; mi < 2; ++mi) {
      int gr = row0 + wave * 32 + mi * 16 + arow_in;
      if (gr >= N) gr = N - 1;
      a[mi] = *(const half8*)(h + (size_t)gr * HID + ks * 32 + kq * 8);
    }
#pragma unroll
    for (int ni = 0; ni < 3; ++ni) {
      int c = ni * 16 + arow_in;
      b[ni] = *(const half8*)&wlds[c][ks * 32 + kq * 8];
    }
#pragma unroll
    for (int mi = 0; mi < 2; ++mi)
#pragma unroll
      for (int ni = 0; ni < 3; ++ni)
        acc[mi][ni] = __builtin_amdgcn_mfma_f32_16x16x32_f16(a[mi], b[ni], acc[mi][ni], 0, 0, 0);
  }

  const int rsub = (lane >> 4) * 4;
#pragma unroll
  for (int ni = 0; ni < 3; ++ni) {
    int col = ni * 16 + (lane & 15);
    if (col >= 40) continue;
    float bv = bl[col];
#pragma unroll
    for (int mi = 0; mi < 2; ++mi) {
#pragma unroll
      for (int j = 0; j < 4; ++j) {
        int gr = row0 + wave * 32 + mi * 16 + rsub + j;
        if (gr < N) out[(size_t)gr * 40 + col] = acc[mi][ni][j] + bv;
      }
    }
  }
}

// ---------------- launch ----------------

extern "C" void kernel_launch(void* const* d_in, const int* in_sizes, int n_in,
                              void* d_out, int out_size, void* d_ws, size_t ws_size,
                              hipStream_t stream) {
  const float* x = (const float*)d_in[0];
  const int* ei = (const int*)d_in[1];
  const float* W0 = (const float*)d_in[2];
  const float* b0 = (const float*)d_in[3];
  const float* Wc = (const float*)d_in[4];
  const float* bc = (const float*)d_in[5];
  const float* Wl = (const float*)d_in[6];
  const float* bl = (const float*)d_in[7];
  float* out = (float*)d_out;

  const int N = in_sizes[0] / 512;
  const int E = in_sizes[1] / 2;
  const int NB = (N + (1 << BSHIFT) - 1) >> BSHIFT;  // 98 for N=100000

  char* ws = (char*)d_ws;
  size_t off = 0;
  auto alloc = [&](size_t bytes) -> char* {
    char* p = ws + off;
    off += (bytes + 511) & ~(size_t)511;
    return p;
  };
  float* dinv = (float*)alloc((size_t)N * 4);
  int* cnt = (int*)alloc((size_t)N * 4);
  int* gcur = (int*)alloc(128 * 4);
  int* colpad = (int*)alloc((size_t)N * 64 * 4);
  int2* bbuf = (int2*)alloc((size_t)NB * BCAP * 8);
  _Float16* hA = (_Float16*)alloc((size_t)N * HID * 2);
  _Float16* hB = (_Float16*)alloc((size_t)N * HID * 2);
  _Float16* hG = (_Float16*)alloc((size_t)N * HID * 2);
  _Float16* W0h = (_Float16*)alloc((size_t)HID * 512 * 2);
  _Float16* Wch = (_Float16*)alloc((size_t)3 * HID * HID * 2);

  const int nb_g = (N + 127) / 128;

  zero_i32<<<1, 256, 0, stream>>>(gcur, 128);
  bin_edges<<<512, 256, 0, stream>>>(ei, gcur, bbuf, E, NB);
  scatter_pad<<<NB, 256, 0, stream>>>(bbuf, gcur, colpad, cnt, dinv, N);

  const int nw0 = HID * 512, nwc = 3 * HID * HID;
  cvt_w2<<<(nw0 + nwc + 255) / 256, 256, 0, stream>>>(W0, nw0, Wc, nwc, W0h, Wch);

  // input layer: hA = relu(x @ W0^T + b0)
  gemm_stream<512, true, 1024><<<256, 1024, 0, stream>>>(x, W0h, b0, nullptr, hA, N, 1);

  _Float16* bufs[2] = {hA, hB};
  int cur = 0;
  for (int l = 0; l < 3; ++l) {
    gemm_stream<128, false, 512><<<1024, 512, 0, stream>>>(
        bufs[cur], Wch + (size_t)l * HID * HID, nullptr, dinv, hG, N, 0);
    agg_pad<<<(N + 3) / 4, 256, 0, stream>>>(hG, cnt, colpad, dinv, bc + (size_t)l * HID,
                                             bufs[1 - cur], N);
    cur = 1 - cur;
  }

  gemm40_mfma<<<nb_g, 256, 0, stream>>>(bufs[cur], Wl, bl, out, N);
}

// Round 16
// 596.443 us; speedup vs baseline: 1.1835x; 1.1835x over previous
//
#include <hip/hip_runtime.h>

#define HID 128
#define BSHIFT 10            // 1024 dst-nodes per bucket
#define BCAP 20480           // bucket capacity (mean 16.3K, sigma ~127 -> 32 sigma)

typedef _Float16 half8 __attribute__((ext_vector_type(8)));
typedef _Float16 half4v __attribute__((ext_vector_type(4)));
typedef float f32x4 __attribute__((ext_vector_type(4)));

__device__ __forceinline__ half8 cvt8(f32x4 f0, f32x4 f1) {
  half8 h;
  h[0] = (_Float16)f0[0]; h[1] = (_Float16)f0[1];
  h[2] = (_Float16)f0[2]; h[3] = (_Float16)f0[3];
  h[4] = (_Float16)f1[0]; h[5] = (_Float16)f1[1];
  h[6] = (_Float16)f1[2]; h[7] = (_Float16)f1[3];
  return h;
}

// ---------------- graph build: two-pass binned scatter ----------------

__global__ __launch_bounds__(256) void zero_i32(int* __restrict__ p, int n) {
  int i = blockIdx.x * 256 + threadIdx.x;
  if (i < n) p[i] = 0;
}

__global__ __launch_bounds__(256) void bin_edges(const int* __restrict__ ei,
                                                 int* __restrict__ gcur,
                                                 int2* __restrict__ buf,
                                                 int E, int NB) {
  __shared__ int bcnt[128];
  __shared__ int bbase[128];
  const int tid = threadIdx.x;

  for (int chunk = blockIdx.x * 2048; chunk < E; chunk += gridDim.x * 2048) {
    if (tid < NB) bcnt[tid] = 0;
    __syncthreads();
    int s[8], d[8], slot[8], b[8];
#pragma unroll
    for (int j = 0; j < 8; ++j) {
      int e = chunk + tid + j * 256;
      if (e < E) {
        s[j] = ei[e];
        d[j] = ei[E + e];
        b[j] = d[j] >> BSHIFT;
        slot[j] = atomicAdd(&bcnt[b[j]], 1);
      } else {
        b[j] = -1;
      }
    }
    __syncthreads();
    if (tid < NB && bcnt[tid] > 0) bbase[tid] = atomicAdd(&gcur[tid], bcnt[tid]);
    __syncthreads();
#pragma unroll
    for (int j = 0; j < 8; ++j) {
      if (b[j] >= 0) {
        int pos = bbase[b[j]] + slot[j];
        if (pos < BCAP) buf[(size_t)b[j] * BCAP + pos] = make_int2(s[j], d[j]);
      }
    }
    __syncthreads();
  }
}

__global__ __launch_bounds__(256) void scatter_pad(const int2* __restrict__ buf,
                                                   const int* __restrict__ gcur,
                                                   int* __restrict__ colpad,
                                                   int* __restrict__ cnt,
                                                   float* __restrict__ dinv, int N) {
  __shared__ int lcnt[1 << BSHIFT];
  const int b = blockIdx.x;
  const int base = b << BSHIFT;
  const int tid = threadIdx.x;
  for (int i = tid; i < (1 << BSHIFT); i += 256) lcnt[i] = 0;
  __syncthreads();

  int ne = gcur[b];
  if (ne > BCAP) ne = BCAP;
  const int2* __restrict__ bb = buf + (size_t)b * BCAP;
  for (int i = tid; i < ne; i += 256) {
    int2 p = bb[i];
    int pos = atomicAdd(&lcnt[p.y - base], 1);
    if (pos < 64) colpad[(size_t)p.y * 64 + pos] = p.x;
  }
  __syncthreads();
  for (int i = tid; i < (1 << BSHIFT); i += 256) {
    int n = base + i;
    if (n < N) {
      int c = lcnt[i];
      cnt[n] = c;
      dinv[n] = rsqrtf((float)(c + 1));
    }
  }
}

// ---------------- weight convert fp32 -> f16 ----------------

__global__ __launch_bounds__(256) void cvt_w2(const float* __restrict__ a, int na,
                                              const float* __restrict__ b, int nb,
                                              _Float16* __restrict__ oa,
                                              _Float16* __restrict__ ob) {
  int i = blockIdx.x * 256 + threadIdx.x;
  if (i < na) oa[i] = (_Float16)a[i];
  else if (i < na + nb) ob[i - na] = (_Float16)b[i - na];
}

// ---------------- streaming MFMA GEMM (barrier-free, spill-free config) ----------------
// out[N][128] = A[N][K] @ W[128][K]^T.  W staged to LDS ONCE (only barrier),
// then each wave independently grid-strides over 16-row tiles: A global->regs
// via 4-slot consume-then-refill pipeline, B from LDS (XOR-swizzled).
// THREAD-COUNT IS THE SPILL LEVER (R15: 1024thr -> 64-VGPR cap -> 487MB scratch;
// R11: 512thr/190-reg set -> spill).  Live set here ~100 regs:
//   K=512: 512 thr (cap 128 > 100, fits; 128KB LDS, grid=256, 1 block/CU)
//   K=128: 256 thr (cap 256, guaranteed; 32KB LDS, high occupancy)

template <int K, bool CONVA, int NTHR>
__global__ __launch_bounds__(NTHR) void gemm_stream(const void* __restrict__ Av,
                                                    const _Float16* __restrict__ Wh,
                                                    const float* __restrict__ bias,
                                                    const float* __restrict__ rowscale,
                                                    _Float16* __restrict__ out,
                                                    int N, int do_relu) {
  constexpr int KS = K / 32;                      // MFMA k-steps
  constexpr int NW = NTHR / 64;                   // waves per block
  __shared__ __align__(16) char Ws[128 * K * 2];  // K=512: 128KB; K=128: 32KB

  const int tid = threadIdx.x;
  const int lane = tid & 63;
  const int wave = tid >> 6;
  const int rsel = lane & 15;  // A row-within-16 / W-row selector / C col
  const int q = lane >> 4;     // k-quarter

  const float* Af = (const float*)Av;
  const _Float16* Ah = (const _Float16*)Av;

  // ---- stage W into LDS (once), swizzled: chunk j -> j ^ (c&7) ----
  constexpr int NCH = 128 * (K / 8);
#pragma unroll
  for (int i = 0; i < NCH / NTHR; ++i) {
    int ch = tid + i * NTHR;
    int c = ch / (K / 8);
    int j = ch % (K / 8);
    *(half8*)(Ws + (size_t)c * (K * 2) + (size_t)(j ^ (c & 7)) * 16) =
        *(const half8*)(Wh + (size_t)c * K + j * 8);
  }
  __syncthreads();

  const int ntiles = (N + 15) / 16;
  for (int t = blockIdx.x * NW + wave; t < ntiles; t += gridDim.x * NW) {
    const int row0 = t * 16;
    int gr = row0 + rsel;
    if (gr >= N) gr = N - 1;  // clamp; stores masked in epilogue
    const char* ap;
    if constexpr (CONVA) ap = (const char*)(Af + (size_t)gr * K + q * 8);
    else                 ap = (const char*)(Ah + (size_t)gr * K + q * 8);

    f32x4 acc[8];
#pragma unroll
    for (int ni = 0; ni < 8; ++ni) acc[ni] = (f32x4){0.f, 0.f, 0.f, 0.f};

    f32x4 fb[4][2];  // [slot][half]  (CONVA)
    half8 hb[4];     // [slot]        (f16)

#define LOADK(SLOT, KSI)                                                     \
  do {                                                                       \
    if constexpr (CONVA) {                                                   \
      fb[SLOT][0] = *(const f32x4*)(ap + (KSI) * 128);                       \
      fb[SLOT][1] = *(const f32x4*)(ap + (KSI) * 128 + 16);                  \
    } else {                                                                 \
      hb[SLOT] = *(const half8*)(ap + (KSI) * 64);                           \
    }                                                                        \
  } while (0)

#define MMAK(SLOT, KSI)                                                      \
  do {                                                                       \
    half8 av;                                                                \
    if constexpr (CONVA) av = cvt8(fb[SLOT][0], fb[SLOT][1]);                \
    else                 av = hb[SLOT];                                      \
    _Pragma("unroll")                                                        \
    for (int ni = 0; ni < 8; ++ni) {                                         \
      int c = ni * 16 + rsel;                                                \
      half8 bv = *(const half8*)(Ws + (size_t)c * (K * 2) +                  \
                                 (size_t)((((KSI) * 4 + q)) ^ (c & 7)) * 16);\
      acc[ni] =                                                              \
          __builtin_amdgcn_mfma_f32_16x16x32_f16(av, bv, acc[ni], 0, 0, 0);  \
    }                                                                        \
  } while (0)

    LOADK(0, 0);
    LOADK(1, 1);
    LOADK(2, 2);
    LOADK(3, 3);
#pragma unroll
    for (int ks = 0; ks < KS; ++ks) {
      MMAK(ks & 3, ks);                              // consume slot (holds ks)
      if (ks + 4 < KS) LOADK((ks + 4) & 3, ks + 4);  // THEN refill for ks+4
    }
#undef LOADK
#undef MMAK

    // epilogue: row = row0 + q*4 + j, col = ni*16 + rsel
    const int rsub = q * 4;
#pragma unroll
    for (int j = 0; j < 4; ++j) {
      int grow = row0 + rsub + j;
      if (grow < N) {
        float rs = rowscale ? rowscale[grow] : 1.0f;
#pragma unroll
        for (int ni = 0; ni < 8; ++ni) {
          int c = ni * 16 + rsel;
          float v = acc[ni][j] * rs;
          if (bias) v += bias[c];
          if (do_relu) v = fmaxf(v, 0.f);
          out[(size_t)grow * HID + c] = (_Float16)v;
        }
      }
    }
  }
}

// ---------------- sparse aggregation: 4 rows per wave-instruction ----------------

__global__ __launch_bounds__(256) void agg_pad(const _Float16* __restrict__ g,
                                               const int* __restrict__ cnt,
                                               const int* __restrict__ colpad,
                                               const float* __restrict__ dinv,
                                               const float* __restrict__ bias,
                                               _Float16* __restrict__ out, int N) {
  int node = blockIdx.x * 4 + (threadIdx.x >> 6);
  if (node >= N) return;
  const int lane = threadIdx.x & 63;
  const int es = lane >> 4;   // edge slot 0..3
  const int ch = lane & 15;   // 16-byte chunk 0..15
  const int deg = cnt[node];
  const int* __restrict__ row = colpad + (size_t)node * 64;

  float acc[8] = {0.f, 0.f, 0.f, 0.f, 0.f, 0.f, 0.f, 0.f};
  int e0 = 0;
  for (; e0 + 16 <= deg; e0 += 16) {
    int i0 = row[e0 + es];
    int i1 = row[e0 + 4 + es];
    int i2 = row[e0 + 8 + es];
    int i3 = row[e0 + 12 + es];
    half8 v0 = *(const half8*)(g + (size_t)i0 * HID + ch * 8);
    half8 v1 = *(const half8*)(g + (size_t)i1 * HID + ch * 8);
    half8 v2 = *(const half8*)(g + (size_t)i2 * HID + ch * 8);
    half8 v3 = *(const half8*)(g + (size_t)i3 * HID + ch * 8);
#pragma unroll
    for (int j = 0; j < 8; ++j)
      acc[j] += ((float)v0[j] + (float)v1[j]) + ((float)v2[j] + (float)v3[j]);
  }
  for (; e0 + 4 <= deg; e0 += 4) {
    int i0 = row[e0 + es];
    half8 v0 = *(const half8*)(g + (size_t)i0 * HID + ch * 8);
#pragma unroll
    for (int j = 0; j < 8; ++j) acc[j] += (float)v0[j];
  }
  const int rem = deg - e0;   // 0..3
  float selfw = 1.0f;
  if (rem > 0) {
    int i0 = (es < rem) ? row[e0 + es] : node;  // pad slots gather the self row
    half8 v0 = *(const half8*)(g + (size_t)i0 * HID + ch * 8);
#pragma unroll
    for (int j = 0; j < 8; ++j) acc[j] += (float)v0[j];
    selfw = 1.0f - (float)(4 - rem);  // compensate the (4-rem) extra self rows
  }

#pragma unroll
  for (int j = 0; j < 8; ++j) {
    acc[j] += __shfl_xor(acc[j], 16, 64);
    acc[j] += __shfl_xor(acc[j], 32, 64);
  }

  if (lane < 16) {
    half8 sv = *(const half8*)(g + (size_t)node * HID + ch * 8);
    const float di = dinv[node];
    half8 o;
#pragma unroll
    for (int j = 0; j < 8; ++j) {
      float v = di * (acc[j] + selfw * (float)sv[j]) + bias[ch * 8 + j];
      o[j] = (_Float16)fmaxf(v, 0.f);
    }
    *(half8*)(out + (size_t)node * HID + ch * 8) = o;
  }
}

// ---------------- final GEMM (MFMA): logits[N][40] = h[N][128] @ Wl[40][128]^T + bl ----------------

__global__ __launch_bounds__(256) void gemm40_mfma(const _Float16* __restrict__ h,
                                                   const float* __restrict__ Wl,
                                                   const float* __restrict__ bl,
                                                   float* __restrict__ out, int N) {
  __shared__ __align__(16) _Float16 wlds[48][136];

  const int tid = threadIdx.x;
  const int lane = tid & 63;
  const int wave = tid >> 6;
  const int row0 = blockIdx.x * 128;

#pragma unroll
  for (int i = 0; i < 6; ++i) {
    int idx4 = tid + i * 256;
    int c = idx4 >> 5;
    int ko = (idx4 & 31) * 4;
    float4 v = make_float4(0.f, 0.f, 0.f, 0.f);
    if (c < 40) v = *(const float4*)(Wl + (size_t)c * HID + ko);
    half4v hv;
    hv[0] = (_Float16)v.x; hv[1] = (_Float16)v.y;
    hv[2] = (_Float16)v.z; hv[3] = (_Float16)v.w;
    *(half4v*)&wlds[c][ko] = hv;
  }
  __syncthreads();

  f32x4 acc[2][3] = {};
  const int arow_in = lane & 15;
  const int kq = lane >> 4;

#pragma unroll
  for (int ks = 0; ks < 4; ++ks) {
    half8 a[2], b[3];
#pragma unroll
    for (int mi = 0; mi < 2; ++mi) {
      int gr = row0 + wave * 32 + mi * 16 + arow_in;
      if (gr >= N) gr = N - 1;
      a[mi] = *(const half8*)(h + (size_t)gr * HID + ks * 32 + kq * 8);
    }
#pragma unroll
    for (int ni = 0; ni < 3; ++ni) {
      int c = ni * 16 + arow_in;
      b[ni] = *(const half8*)&wlds[c][ks * 32 + kq * 8];
    }
#pragma unroll
    for (int mi = 0; mi < 2; ++mi)
#pragma unroll
      for (int ni = 0; ni < 3; ++ni)
        acc[mi][ni] = __builtin_amdgcn_mfma_f32_16x16x32_f16(a[mi], b[ni], acc[mi][ni], 0, 0, 0);
  }

  const int rsub = (lane >> 4) * 4;
#pragma unroll
  for (int ni = 0; ni < 3; ++ni) {
    int col = ni * 16 + (lane & 15);
    if (col >= 40) continue;
    float bv = bl[col];
#pragma unroll
    for (int mi = 0; mi < 2; ++mi) {
#pragma unroll
      for (int j = 0; j < 4; ++j) {
        int gr = row0 + wave * 32 + mi * 16 + rsub + j;
        if (gr < N) out[(size_t)gr * 40 + col] = acc[mi][ni][j] + bv;
      }
    }
  }
}

// ---------------- launch ----------------

extern "C" void kernel_launch(void* const* d_in, const int* in_sizes, int n_in,
                              void* d_out, int out_size, void* d_ws, size_t ws_size,
                              hipStream_t stream) {
  const float* x = (const float*)d_in[0];
  const int* ei = (const int*)d_in[1];
  const float* W0 = (const float*)d_in[2];
  const float* b0 = (const float*)d_in[3];
  const float* Wc = (const float*)d_in[4];
  const float* bc = (const float*)d_in[5];
  const float* Wl = (const float*)d_in[6];
  const float* bl = (const float*)d_in[7];
  float* out = (float*)d_out;

  const int N = in_sizes[0] / 512;
  const int E = in_sizes[1] / 2;
  const int NB = (N + (1 << BSHIFT) - 1) >> BSHIFT;  // 98 for N=100000

  char* ws = (char*)d_ws;
  size_t off = 0;
  auto alloc = [&](size_t bytes) -> char* {
    char* p = ws + off;
    off += (bytes + 511) & ~(size_t)511;
    return p;
  };
  float* dinv = (float*)alloc((size_t)N * 4);
  int* cnt = (int*)alloc((size_t)N * 4);
  int* gcur = (int*)alloc(128 * 4);
  int* colpad = (int*)alloc((size_t)N * 64 * 4);
  int2* bbuf = (int2*)alloc((size_t)NB * BCAP * 8);
  _Float16* hA = (_Float16*)alloc((size_t)N * HID * 2);
  _Float16* hB = (_Float16*)alloc((size_t)N * HID * 2);
  _Float16* hG = (_Float16*)alloc((size_t)N * HID * 2);
  _Float16* W0h = (_Float16*)alloc((size_t)HID * 512 * 2);
  _Float16* Wch = (_Float16*)alloc((size_t)3 * HID * HID * 2);

  const int nb_g = (N + 127) / 128;

  zero_i32<<<1, 256, 0, stream>>>(gcur, 128);
  bin_edges<<<512, 256, 0, stream>>>(ei, gcur, bbuf, E, NB);
  scatter_pad<<<NB, 256, 0, stream>>>(bbuf, gcur, colpad, cnt, dinv, N);

  const int nw0 = HID * 512, nwc = 3 * HID * HID;
  cvt_w2<<<(nw0 + nwc + 255) / 256, 256, 0, stream>>>(W0, nw0, Wc, nwc, W0h, Wch);

  // input layer: hA = relu(x @ W0^T + b0)  — 512 thr (VGPR cap 128), grid=256
  gemm_stream<512, true, 512><<<256, 512, 0, stream>>>(x, W0h, b0, nullptr, hA, N, 1);

  _Float16* bufs[2] = {hA, hB};
  int cur = 0;
  for (int l = 0; l < 3; ++l) {
    // 256 thr (VGPR cap 256), 32KB LDS -> high occupancy
    gemm_stream<128, false, 256><<<2048, 256, 0, stream>>>(
        bufs[cur], Wch + (size_t)l * HID * HID, nullptr, dinv, hG, N, 0);
    agg_pad<<<(N + 3) / 4, 256, 0, stream>>>(hG, cnt, colpad, dinv, bc + (size_t)l * HID,
                                             bufs[1 - cur], N);
    cur = 1 - cur;
  }

  gemm40_mfma<<<nb_g, 256, 0, stream>>>(bufs[cur], Wl, bl, out, N);
}

// Round 17
// 370.459 us; speedup vs baseline: 1.9054x; 1.6100x over previous
//
#include <hip/hip_runtime.h>

#define HID 128
#define BSHIFT 10            // 1024 dst-nodes per bucket
#define BCAP 20480           // bucket capacity (mean 16.3K, sigma ~127 -> 32 sigma)

typedef _Float16 half8 __attribute__((ext_vector_type(8)));
typedef _Float16 half4v __attribute__((ext_vector_type(4)));
typedef float f32x4 __attribute__((ext_vector_type(4)));

__device__ __forceinline__ half8 cvt8(f32x4 f0, f32x4 f1) {
  half8 h;
  h[0] = (_Float16)f0[0]; h[1] = (_Float16)f0[1];
  h[2] = (_Float16)f0[2]; h[3] = (_Float16)f0[3];
  h[4] = (_Float16)f1[0]; h[5] = (_Float16)f1[1];
  h[6] = (_Float16)f1[2]; h[7] = (_Float16)f1[3];
  return h;
}

// async global->LDS, 16B per lane; LDS dest = wave-uniform base + lane*16
#define GLDS16(gp, lp)                                                        \
  __builtin_amdgcn_global_load_lds(                                           \
      (const __attribute__((address_space(1))) void*)(gp),                    \
      (__attribute__((address_space(3))) void*)(lp), 16, 0, 0)

// ---------------- graph build: two-pass binned scatter ----------------

__global__ __launch_bounds__(256) void zero_i32(int* __restrict__ p, int n) {
  int i = blockIdx.x * 256 + threadIdx.x;
  if (i < n) p[i] = 0;
}

__global__ __launch_bounds__(256) void bin_edges(const int* __restrict__ ei,
                                                 int* __restrict__ gcur,
                                                 int2* __restrict__ buf,
                                                 int E, int NB) {
  __shared__ int bcnt[128];
  __shared__ int bbase[128];
  const int tid = threadIdx.x;

  for (int chunk = blockIdx.x * 2048; chunk < E; chunk += gridDim.x * 2048) {
    if (tid < NB) bcnt[tid] = 0;
    __syncthreads();
    int s[8], d[8], slot[8], b[8];
#pragma unroll
    for (int j = 0; j < 8; ++j) {
      int e = chunk + tid + j * 256;
      if (e < E) {
        s[j] = ei[e];
        d[j] = ei[E + e];
        b[j] = d[j] >> BSHIFT;
        slot[j] = atomicAdd(&bcnt[b[j]], 1);
      } else {
        b[j] = -1;
      }
    }
    __syncthreads();
    if (tid < NB && bcnt[tid] > 0) bbase[tid] = atomicAdd(&gcur[tid], bcnt[tid]);
    __syncthreads();
#pragma unroll
    for (int j = 0; j < 8; ++j) {
      if (b[j] >= 0) {
        int pos = bbase[b[j]] + slot[j];
        if (pos < BCAP) buf[(size_t)b[j] * BCAP + pos] = make_int2(s[j], d[j]);
      }
    }
    __syncthreads();
  }
}

__global__ __launch_bounds__(256) void scatter_pad(const int2* __restrict__ buf,
                                                   const int* __restrict__ gcur,
                                                   int* __restrict__ colpad,
                                                   int* __restrict__ cnt,
                                                   float* __restrict__ dinv, int N) {
  __shared__ int lcnt[1 << BSHIFT];
  const int b = blockIdx.x;
  const int base = b << BSHIFT;
  const int tid = threadIdx.x;
  for (int i = tid; i < (1 << BSHIFT); i += 256) lcnt[i] = 0;
  __syncthreads();

  int ne = gcur[b];
  if (ne > BCAP) ne = BCAP;
  const int2* __restrict__ bb = buf + (size_t)b * BCAP;
  for (int i = tid; i < ne; i += 256) {
    int2 p = bb[i];
    int pos = atomicAdd(&lcnt[p.y - base], 1);
    if (pos < 64) colpad[(size_t)p.y * 64 + pos] = p.x;
  }
  __syncthreads();
  for (int i = tid; i < (1 << BSHIFT); i += 256) {
    int n = base + i;
    if (n < N) {
      int c = lcnt[i];
      cnt[n] = c;
      dinv[n] = rsqrtf((float)(c + 1));
    }
  }
}

// ---------------- weight convert fp32 -> f16 ----------------

__global__ __launch_bounds__(256) void cvt_w2(const float* __restrict__ a, int na,
                                              const float* __restrict__ b, int nb,
                                              _Float16* __restrict__ oa,
                                              _Float16* __restrict__ ob) {
  int i = blockIdx.x * 256 + threadIdx.x;
  if (i < na) oa[i] = (_Float16)a[i];
  else if (i < na + nb) ob[i - na] = (_Float16)b[i - na];
}

// ---------------- layer-0 GEMM: hA = relu(x[N][512] @ W0h[128][512]^T + b0) ----------------
// R14 structure with SINGLE-buffered B: As 64KB + Bs 16KB = 80KB LDS ->
// exactly 2 blocks/CU (vs R14's 96KB -> 1) = 2x resident waves for this
// latency-bound kernel; the co-resident block's waves cover the barrier gaps.

__global__ __launch_bounds__(512) void gemm512_panel(const float* __restrict__ Af,
                                                     const _Float16* __restrict__ Wh,
                                                     const float* __restrict__ b0,
                                                     _Float16* __restrict__ out, int N) {
  __shared__ __align__(16) char As[64 * 512 * 2];    // 64KB f16, chunk-XOR swizzled
  __shared__ __align__(16) char Bs[128 * 64 * 2];    // 16KB (single 64-k chunk)

  const int tid = threadIdx.x;
  const int lane = tid & 63;
  const int wave = tid >> 6;
  const int wgrp = wave & 3;          // row-group (16 rows)
  const int coff = (wave >> 2) * 64;  // col half
  const int row0 = blockIdx.x * 64;

  // ---- stage A panel: 64 rows x 512 f32, contiguous; cvt to f16 ----
#pragma unroll
  for (int p = 0; p < 8; ++p) {
    int idx = p * 512 + tid;        // float8 index, 4096 total
    int r = idx >> 6;               // 64 float8 per row
    int j = idx & 63;               // chunk within row
    int grow = row0 + r; if (grow >= N) grow = N - 1;
    const float* src = Af + (size_t)grow * 512 + j * 8;
    f32x4 f0 = *(const f32x4*)(src);
    f32x4 f1 = *(const f32x4*)(src + 4);
    *(half8*)(As + r * 1024 + ((j ^ (r & 7)) << 4)) = cvt8(f0, f1);
  }

  f32x4 acc[4] = {};

  for (int k8 = 0; k8 < 8; ++k8) {
    // stage B chunk k8 (glds): 128 rows x 64 f16; 16 rows/wave, 2 instrs
#pragma unroll
    for (int i = 0; i < 2; ++i) {
      int r = wave * 16 + i * 8 + (lane >> 3);
      int csw = (lane & 7) ^ (r & 7);
      GLDS16(Wh + (size_t)r * 512 + k8 * 64 + csw * 8,
             Bs + (wave * 16 + i * 8) * 128);
    }
    __syncthreads();  // drains glds (and A-writes on first iter)

#pragma unroll
    for (int sub = 0; sub < 2; ++sub) {
      int r = wgrp * 16 + (lane & 15);
      int ja = k8 * 8 + sub * 4 + (lane >> 4);
      half8 a = *(const half8*)(As + r * 1024 + ((ja ^ (r & 7)) << 4));
      int jb = sub * 4 + (lane >> 4);
#pragma unroll
      for (int ni = 0; ni < 4; ++ni) {
        int c = coff + ni * 16 + (lane & 15);
        half8 b = *(const half8*)(Bs + c * 128 + ((jb ^ (c & 7)) << 4));
        acc[ni] = __builtin_amdgcn_mfma_f32_16x16x32_f16(a, b, acc[ni], 0, 0, 0);
      }
    }
    __syncthreads();  // all waves done reading Bs before next-stage overwrite
  }

  // epilogue: row = row0 + wgrp*16 + (lane>>4)*4 + j, col = coff + ni*16 + (lane&15)
  const int rsub = (lane >> 4) * 4;
#pragma unroll
  for (int j = 0; j < 4; ++j) {
    int grow = row0 + wgrp * 16 + rsub + j;
    if (grow < N) {
#pragma unroll
      for (int ni = 0; ni < 4; ++ni) {
        int c = coff + ni * 16 + (lane & 15);
        float v = acc[ni][j] + b0[c];
        out[(size_t)grow * HID + c] = (_Float16)fmaxf(v, 0.f);
      }
    }
  }
}

// ---------------- mid GEMM: g = dinv * (h[N][128] @ Wc[128][128]^T) ----------------
// Whole A-panel (16KB) + whole B (32KB) staged via glds once; ONE barrier; 4 substeps.

__global__ __launch_bounds__(512) void gemm128_panel(const _Float16* __restrict__ Ah,
                                                     const _Float16* __restrict__ Wh,
                                                     const float* __restrict__ rowscale,
                                                     _Float16* __restrict__ out, int N) {
  __shared__ __align__(16) char As[64 * 128 * 2];   // 16KB
  __shared__ __align__(16) char Bs[128 * 128 * 2];  // 32KB

  const int tid = threadIdx.x;
  const int lane = tid & 63;
  const int wave = tid >> 6;
  const int wgrp = wave & 3;
  const int coff = (wave >> 2) * 64;
  const int row0 = blockIdx.x * 64;

  // A: 64 rows x 16 chunks; per wave-instr: 4 rows x 16 chunks; 2 instrs (8 rows/wave)
#pragma unroll
  for (int i = 0; i < 2; ++i) {
    int r = wave * 8 + i * 4 + (lane >> 4);
    int grow = row0 + r; if (grow >= N) grow = N - 1;
    int csw = (lane & 15) ^ (r & 7);
    GLDS16(Ah + (size_t)grow * 128 + csw * 8, As + (wave * 8 + i * 4) * 256);
  }
  // B: 128 rows x 16 chunks; 4 instrs (16 rows/wave)
#pragma unroll
  for (int i = 0; i < 4; ++i) {
    int r = wave * 16 + i * 4 + (lane >> 4);
    int csw = (lane & 15) ^ (r & 7);
    GLDS16(Wh + (size_t)r * 128 + csw * 8, Bs + (wave * 16 + i * 4) * 256);
  }
  __syncthreads();

  f32x4 acc[4] = {};
#pragma unroll
  for (int sub = 0; sub < 4; ++sub) {
    int r = wgrp * 16 + (lane & 15);
    int j = sub * 4 + (lane >> 4);
    half8 a = *(const half8*)(As + r * 256 + ((j ^ (r & 7)) << 4));
#pragma unroll
    for (int ni = 0; ni < 4; ++ni) {
      int c = coff + ni * 16 + (lane & 15);
      half8 b = *(const half8*)(Bs + c * 256 + ((j ^ (c & 7)) << 4));
      acc[ni] = __builtin_amdgcn_mfma_f32_16x16x32_f16(a, b, acc[ni], 0, 0, 0);
    }
  }

  const int rsub = (lane >> 4) * 4;
#pragma unroll
  for (int j = 0; j < 4; ++j) {
    int grow = row0 + wgrp * 16 + rsub + j;
    if (grow < N) {
      float rs = rowscale[grow];
#pragma unroll
      for (int ni = 0; ni < 4; ++ni) {
        int c = coff + ni * 16 + (lane & 15);
        out[(size_t)grow * HID + c] = (_Float16)(acc[ni][j] * rs);
      }
    }
  }
}

// ---------------- sparse aggregation: 4 rows per wave-instruction ----------------

__global__ __launch_bounds__(256) void agg_pad(const _Float16* __restrict__ g,
                                               const int* __restrict__ cnt,
                                               const int* __restrict__ colpad,
                                               const float* __restrict__ dinv,
                                               const float* __restrict__ bias,
                                               _Float16* __restrict__ out, int N) {
  int node = blockIdx.x * 4 + (threadIdx.x >> 6);
  if (node >= N) return;
  const int lane = threadIdx.x & 63;
  const int es = lane >> 4;   // edge slot 0..3
  const int ch = lane & 15;   // 16-byte chunk 0..15
  const int deg = cnt[node];
  const int* __restrict__ row = colpad + (size_t)node * 64;

  float acc[8] = {0.f, 0.f, 0.f, 0.f, 0.f, 0.f, 0.f, 0.f};
  int e0 = 0;
  for (; e0 + 16 <= deg; e0 += 16) {
    int i0 = row[e0 + es];
    int i1 = row[e0 + 4 + es];
    int i2 = row[e0 + 8 + es];
    int i3 = row[e0 + 12 + es];
    half8 v0 = *(const half8*)(g + (size_t)i0 * HID + ch * 8);
    half8 v1 = *(const half8*)(g + (size_t)i1 * HID + ch * 8);
    half8 v2 = *(const half8*)(g + (size_t)i2 * HID + ch * 8);
    half8 v3 = *(const half8*)(g + (size_t)i3 * HID + ch * 8);
#pragma unroll
    for (int j = 0; j < 8; ++j)
      acc[j] += ((float)v0[j] + (float)v1[j]) + ((float)v2[j] + (float)v3[j]);
  }
  for (; e0 + 4 <= deg; e0 += 4) {
    int i0 = row[e0 + es];
    half8 v0 = *(const half8*)(g + (size_t)i0 * HID + ch * 8);
#pragma unroll
    for (int j = 0; j < 8; ++j) acc[j] += (float)v0[j];
  }
  const int rem = deg - e0;   // 0..3
  float selfw = 1.0f;
  if (rem > 0) {
    int i0 = (es < rem) ? row[e0 + es] : node;  // pad slots gather the self row
    half8 v0 = *(const half8*)(g + (size_t)i0 * HID + ch * 8);
#pragma unroll
    for (int j = 0; j < 8; ++j) acc[j] += (float)v0[j];
    selfw = 1.0f - (float)(4 - rem);  // compensate the (4-rem) extra self rows
  }

#pragma unroll
  for (int j = 0; j < 8; ++j) {
    acc[j] += __shfl_xor(acc[j], 16, 64);
    acc[j] += __shfl_xor(acc[j], 32, 64);
  }

  if (lane < 16) {
    half8 sv = *(const half8*)(g + (size_t)node * HID + ch * 8);
    const float di = dinv[node];
    half8 o;
#pragma unroll
    for (int j = 0; j < 8; ++j) {
      float v = di * (acc[j] + selfw * (float)sv[j]) + bias[ch * 8 + j];
      o[j] = (_Float16)fmaxf(v, 0.f);
    }
    *(half8*)(out + (size_t)node * HID + ch * 8) = o;
  }
}

// ---------------- final GEMM (MFMA): logits[N][40] = h[N][128] @ Wl[40][128]^T + bl ----------------

__global__ __launch_bounds__(256) void gemm40_mfma(const _Float16* __restrict__ h,
                                                   const float* __restrict__ Wl,
                                                   const float* __restrict__ bl,
                                                   float* __restrict__ out, int N) {
  __shared__ __align__(16) _Float16 wlds[48][136];

  const int tid = threadIdx.x;
  const int lane = tid & 63;
  const int wave = tid >> 6;
  const int row0 = blockIdx.x * 128;

#pragma unroll
  for (int i = 0; i < 6; ++i) {
    int idx4 = tid + i * 256;
    int c = idx4 >> 5;
    int ko = (idx4 & 31) * 4;
    float4 v = make_float4(0.f, 0.f, 0.f, 0.f);
    if (c < 40) v = *(const float4*)(Wl + (size_t)c * HID + ko);
    half4v hv;
    hv[0] = (_Float16)v.x; hv[1] = (_Float16)v.y;
    hv[2] = (_Float16)v.z; hv[3] = (_Float16)v.w;
    *(half4v*)&wlds[c][ko] = hv;
  }
  __syncthreads();

  f32x4 acc[2][3] = {};
  const int arow_in = lane & 15;
  const int kq = lane >> 4;

#pragma unroll
  for (int ks = 0; ks < 4; ++ks) {
    half8 a[2], b[3];
#pragma unroll
    for (int mi = 0; mi < 2; ++mi) {
      int gr = row0 + wave * 32 + mi * 16 + arow_in;
      if (gr >= N) gr = N - 1;
      a[mi] = *(const half8*)(h + (size_t)gr * HID + ks * 32 + kq * 8);
    }
#pragma unroll
    for (int ni = 0; ni < 3; ++ni) {
      int c = ni * 16 + arow_in;
      b[ni] = *(const half8*)&wlds[c][ks * 32 + kq * 8];
    }
#pragma unroll
    for (int mi = 0; mi < 2; ++mi)
#pragma unroll
      for (int ni = 0; ni < 3; ++ni)
        acc[mi][ni] = __builtin_amdgcn_mfma_f32_16x16x32_f16(a[mi], b[ni], acc[mi][ni], 0, 0, 0);
  }

  const int rsub = (lane >> 4) * 4;
#pragma unroll
  for (int ni = 0; ni < 3; ++ni) {
    int col = ni * 16 + (lane & 15);
    if (col >= 40) continue;
    float bv = bl[col];
#pragma unroll
    for (int mi = 0; mi < 2; ++mi) {
#pragma unroll
      for (int j = 0; j < 4; ++j) {
        int gr = row0 + wave * 32 + mi * 16 + rsub + j;
        if (gr < N) out[(size_t)gr * 40 + col] = acc[mi][ni][j] + bv;
      }
    }
  }
}

// ---------------- launch ----------------

extern "C" void kernel_launch(void* const* d_in, const int* in_sizes, int n_in,
                              void* d_out, int out_size, void* d_ws, size_t ws_size,
                              hipStream_t stream) {
  const float* x = (const float*)d_in[0];
  const int* ei = (const int*)d_in[1];
  const float* W0 = (const float*)d_in[2];
  const float* b0 = (const float*)d_in[3];
  const float* Wc = (const float*)d_in[4];
  const float* bc = (const float*)d_in[5];
  const float* Wl = (const float*)d_in[6];
  const float* bl = (const float*)d_in[7];
  float* out = (float*)d_out;

  const int N = in_sizes[0] / 512;
  const int E = in_sizes[1] / 2;
  const int NB = (N + (1 << BSHIFT) - 1) >> BSHIFT;  // 98 for N=100000

  char* ws = (char*)d_ws;
  size_t off = 0;
  auto alloc = [&](size_t bytes) -> char* {
    char* p = ws + off;
    off += (bytes + 511) & ~(size_t)511;
    return p;
  };
  float* dinv = (float*)alloc((size_t)N * 4);
  int* cnt = (int*)alloc((size_t)N * 4);
  int* gcur = (int*)alloc(128 * 4);
  int* colpad = (int*)alloc((size_t)N * 64 * 4);
  int2* bbuf = (int2*)alloc((size_t)NB * BCAP * 8);
  _Float16* hA = (_Float16*)alloc((size_t)N * HID * 2);
  _Float16* hB = (_Float16*)alloc((size_t)N * HID * 2);
  _Float16* hG = (_Float16*)alloc((size_t)N * HID * 2);
  _Float16* W0h = (_Float16*)alloc((size_t)HID * 512 * 2);
  _Float16* Wch = (_Float16*)alloc((size_t)3 * HID * HID * 2);

  const int nb_g = (N + 127) / 128;
  const int nb64 = (N + 63) / 64;

  zero_i32<<<1, 256, 0, stream>>>(gcur, 128);
  bin_edges<<<512, 256, 0, stream>>>(ei, gcur, bbuf, E, NB);
  scatter_pad<<<NB, 256, 0, stream>>>(bbuf, gcur, colpad, cnt, dinv, N);

  const int nw0 = HID * 512, nwc = 3 * HID * HID;
  cvt_w2<<<(nw0 + nwc + 255) / 256, 256, 0, stream>>>(W0, nw0, Wc, nwc, W0h, Wch);

  // input layer: hA = relu(x @ W0^T + b0)
  gemm512_panel<<<nb64, 512, 0, stream>>>(x, W0h, b0, hA, N);

  _Float16* bufs[2] = {hA, hB};
  int cur = 0;
  for (int l = 0; l < 3; ++l) {
    gemm128_panel<<<nb64, 512, 0, stream>>>(bufs[cur], Wch + (size_t)l * HID * HID,
                                            dinv, hG, N);
    agg_pad<<<(N + 3) / 4, 256, 0, stream>>>(hG, cnt, colpad, dinv, bc + (size_t)l * HID,
                                             bufs[1 - cur], N);
    cur = 1 - cur;
  }

  gemm40_mfma<<<nb_g, 256, 0, stream>>>(bufs[cur], Wl, bl, out, N);
}

// Round 18
// 363.539 us; speedup vs baseline: 1.9417x; 1.0190x over previous
//
#include <hip/hip_runtime.h>

#define HID 128
#define BSHIFT 10            // 1024 dst-nodes per bucket
#define BCAP 20480           // bucket capacity (mean 16.3K, sigma ~127 -> 32 sigma)

typedef _Float16 half8 __attribute__((ext_vector_type(8)));
typedef _Float16 half4v __attribute__((ext_vector_type(4)));
typedef float f32x4 __attribute__((ext_vector_type(4)));

__device__ __forceinline__ half8 cvt8(f32x4 f0, f32x4 f1) {
  half8 h;
  h[0] = (_Float16)f0[0]; h[1] = (_Float16)f0[1];
  h[2] = (_Float16)f0[2]; h[3] = (_Float16)f0[3];
  h[4] = (_Float16)f1[0]; h[5] = (_Float16)f1[1];
  h[6] = (_Float16)f1[2]; h[7] = (_Float16)f1[3];
  return h;
}

// async global->LDS, 16B per lane; LDS dest = wave-uniform base + lane*16
#define GLDS16(gp, lp)                                                        \
  __builtin_amdgcn_global_load_lds(                                           \
      (const __attribute__((address_space(1))) void*)(gp),                    \
      (__attribute__((address_space(3))) void*)(lp), 16, 0, 0)

// ---------------- graph build: two-pass binned scatter ----------------

__global__ __launch_bounds__(256) void zero_i32(int* __restrict__ p, int n) {
  int i = blockIdx.x * 256 + threadIdx.x;
  if (i < n) p[i] = 0;
}

__global__ __launch_bounds__(256) void bin_edges(const int* __restrict__ ei,
                                                 int* __restrict__ gcur,
                                                 int2* __restrict__ buf,
                                                 int E, int NB) {
  __shared__ int bcnt[128];
  __shared__ int bbase[128];
  const int tid = threadIdx.x;

  for (int chunk = blockIdx.x * 2048; chunk < E; chunk += gridDim.x * 2048) {
    if (tid < NB) bcnt[tid] = 0;
    __syncthreads();
    int s[8], d[8], slot[8], b[8];
#pragma unroll
    for (int j = 0; j < 8; ++j) {
      int e = chunk + tid + j * 256;
      if (e < E) {
        s[j] = ei[e];
        d[j] = ei[E + e];
        b[j] = d[j] >> BSHIFT;
        slot[j] = atomicAdd(&bcnt[b[j]], 1);
      } else {
        b[j] = -1;
      }
    }
    __syncthreads();
    if (tid < NB && bcnt[tid] > 0) bbase[tid] = atomicAdd(&gcur[tid], bcnt[tid]);
    __syncthreads();
#pragma unroll
    for (int j = 0; j < 8; ++j) {
      if (b[j] >= 0) {
        int pos = bbase[b[j]] + slot[j];
        if (pos < BCAP) buf[(size_t)b[j] * BCAP + pos] = make_int2(s[j], d[j]);
      }
    }
    __syncthreads();
  }
}

__global__ __launch_bounds__(256) void scatter_pad(const int2* __restrict__ buf,
                                                   const int* __restrict__ gcur,
                                                   int* __restrict__ colpad,
                                                   int* __restrict__ cnt,
                                                   float* __restrict__ dinv, int N) {
  __shared__ int lcnt[1 << BSHIFT];
  const int b = blockIdx.x;
  const int base = b << BSHIFT;
  const int tid = threadIdx.x;
  for (int i = tid; i < (1 << BSHIFT); i += 256) lcnt[i] = 0;
  __syncthreads();

  int ne = gcur[b];
  if (ne > BCAP) ne = BCAP;
  const int2* __restrict__ bb = buf + (size_t)b * BCAP;
  for (int i = tid; i < ne; i += 256) {
    int2 p = bb[i];
    int pos = atomicAdd(&lcnt[p.y - base], 1);
    if (pos < 64) colpad[(size_t)p.y * 64 + pos] = p.x;
  }
  __syncthreads();
  for (int i = tid; i < (1 << BSHIFT); i += 256) {
    int n = base + i;
    if (n < N) {
      int c = lcnt[i];
      cnt[n] = c;
      dinv[n] = rsqrtf((float)(c + 1));
    }
  }
}

// ---------------- weight convert fp32 -> f16 ----------------

__global__ __launch_bounds__(256) void cvt_w2(const float* __restrict__ a, int na,
                                              const float* __restrict__ b, int nb,
                                              _Float16* __restrict__ oa,
                                              _Float16* __restrict__ ob) {
  int i = blockIdx.x * 256 + threadIdx.x;
  if (i < na) oa[i] = (_Float16)a[i];
  else if (i < na + nb) ob[i - na] = (_Float16)b[i - na];
}

// ---------------- layer-0 GEMM: hA = relu(x[N][512] @ W0h[128][512]^T + b0) ----------------
// R17 structure with HALVED A-panel: As 32KB (64 rows x 256 k) + Bs 16KB =
// 48KB LDS -> 3 blocks/CU (6 waves/SIMD, +50% resident waves vs R17's 2).
// Outer kk loop re-stages the A half (contiguous 1KB/row reads).

__global__ __launch_bounds__(512) void gemm512_panel(const float* __restrict__ Af,
                                                     const _Float16* __restrict__ Wh,
                                                     const float* __restrict__ b0,
                                                     _Float16* __restrict__ out, int N) {
  __shared__ __align__(16) char As[64 * 256 * 2];    // 32KB f16, chunk-XOR swizzled
  __shared__ __align__(16) char Bs[128 * 64 * 2];    // 16KB (single 64-k chunk)

  const int tid = threadIdx.x;
  const int lane = tid & 63;
  const int wave = tid >> 6;
  const int wgrp = wave & 3;          // row-group (16 rows)
  const int coff = (wave >> 2) * 64;  // col half
  const int row0 = blockIdx.x * 64;

  f32x4 acc[4] = {};

  for (int kk = 0; kk < 2; ++kk) {
    // ---- stage A half-panel: 64 rows x 256 f32 (1KB/row contiguous); cvt f16 ----
#pragma unroll
    for (int p = 0; p < 4; ++p) {
      int idx = p * 512 + tid;        // float8 index, 2048 total
      int r = idx >> 5;               // 32 float8 per row-half
      int j = idx & 31;               // chunk within row-half
      int grow = row0 + r; if (grow >= N) grow = N - 1;
      const float* src = Af + (size_t)grow * 512 + kk * 256 + j * 8;
      f32x4 f0 = *(const f32x4*)(src);
      f32x4 f1 = *(const f32x4*)(src + 4);
      *(half8*)(As + r * 512 + ((j ^ (r & 7)) << 4)) = cvt8(f0, f1);
    }

    for (int k8 = 0; k8 < 4; ++k8) {
      // stage B chunk (kk*4+k8) via glds: 128 rows x 64 f16; 16 rows/wave
#pragma unroll
      for (int i = 0; i < 2; ++i) {
        int r = wave * 16 + i * 8 + (lane >> 3);
        int csw = (lane & 7) ^ (r & 7);
        GLDS16(Wh + (size_t)r * 512 + (kk * 4 + k8) * 64 + csw * 8,
               Bs + (wave * 16 + i * 8) * 128);
      }
      __syncthreads();  // drains glds + A ds_writes

#pragma unroll
      for (int sub = 0; sub < 2; ++sub) {
        int r = wgrp * 16 + (lane & 15);
        int ja = k8 * 8 + sub * 4 + (lane >> 4);   // within [0,32)
        half8 a = *(const half8*)(As + r * 512 + ((ja ^ (r & 7)) << 4));
        int jb = sub * 4 + (lane >> 4);
#pragma unroll
        for (int ni = 0; ni < 4; ++ni) {
          int c = coff + ni * 16 + (lane & 15);
          half8 b = *(const half8*)(Bs + c * 128 + ((jb ^ (c & 7)) << 4));
          acc[ni] = __builtin_amdgcn_mfma_f32_16x16x32_f16(a, b, acc[ni], 0, 0, 0);
        }
      }
      __syncthreads();  // all waves done reading As/Bs before overwrite
    }
  }

  // epilogue: row = row0 + wgrp*16 + (lane>>4)*4 + j, col = coff + ni*16 + (lane&15)
  const int rsub = (lane >> 4) * 4;
#pragma unroll
  for (int j = 0; j < 4; ++j) {
    int grow = row0 + wgrp * 16 + rsub + j;
    if (grow < N) {
#pragma unroll
      for (int ni = 0; ni < 4; ++ni) {
        int c = coff + ni * 16 + (lane & 15);
        float v = acc[ni][j] + b0[c];
        out[(size_t)grow * HID + c] = (_Float16)fmaxf(v, 0.f);
      }
    }
  }
}

// ---------------- mid GEMM: g = dinv * (h[N][128] @ Wc[128][128]^T) ----------------
// Whole A-panel (16KB) + whole B (32KB) staged via glds once; ONE barrier; 48KB -> 3 blocks/CU.

__global__ __launch_bounds__(512) void gemm128_panel(const _Float16* __restrict__ Ah,
                                                     const _Float16* __restrict__ Wh,
                                                     const float* __restrict__ rowscale,
                                                     _Float16* __restrict__ out, int N) {
  __shared__ __align__(16) char As[64 * 128 * 2];   // 16KB
  __shared__ __align__(16) char Bs[128 * 128 * 2];  // 32KB

  const int tid = threadIdx.x;
  const int lane = tid & 63;
  const int wave = tid >> 6;
  const int wgrp = wave & 3;
  const int coff = (wave >> 2) * 64;
  const int row0 = blockIdx.x * 64;

  // A: 64 rows x 16 chunks; per wave-instr: 4 rows x 16 chunks; 2 instrs (8 rows/wave)
#pragma unroll
  for (int i = 0; i < 2; ++i) {
    int r = wave * 8 + i * 4 + (lane >> 4);
    int grow = row0 + r; if (grow >= N) grow = N - 1;
    int csw = (lane & 15) ^ (r & 7);
    GLDS16(Ah + (size_t)grow * 128 + csw * 8, As + (wave * 8 + i * 4) * 256);
  }
  // B: 128 rows x 16 chunks; 4 instrs (16 rows/wave)
#pragma unroll
  for (int i = 0; i < 4; ++i) {
    int r = wave * 16 + i * 4 + (lane >> 4);
    int csw = (lane & 15) ^ (r & 7);
    GLDS16(Wh + (size_t)r * 128 + csw * 8, Bs + (wave * 16 + i * 4) * 256);
  }
  __syncthreads();

  f32x4 acc[4] = {};
#pragma unroll
  for (int sub = 0; sub < 4; ++sub) {
    int r = wgrp * 16 + (lane & 15);
    int j = sub * 4 + (lane >> 4);
    half8 a = *(const half8*)(As + r * 256 + ((j ^ (r & 7)) << 4));
#pragma unroll
    for (int ni = 0; ni < 4; ++ni) {
      int c = coff + ni * 16 + (lane & 15);
      half8 b = *(const half8*)(Bs + c * 256 + ((j ^ (c & 7)) << 4));
      acc[ni] = __builtin_amdgcn_mfma_f32_16x16x32_f16(a, b, acc[ni], 0, 0, 0);
    }
  }

  const int rsub = (lane >> 4) * 4;
#pragma unroll
  for (int j = 0; j < 4; ++j) {
    int grow = row0 + wgrp * 16 + rsub + j;
    if (grow < N) {
      float rs = rowscale[grow];
#pragma unroll
      for (int ni = 0; ni < 4; ++ni) {
        int c = coff + ni * 16 + (lane & 15);
        out[(size_t)grow * HID + c] = (_Float16)(acc[ni][j] * rs);
      }
    }
  }
}

// ---------------- sparse aggregation: 4 rows per wave-instruction ----------------

__global__ __launch_bounds__(256) void agg_pad(const _Float16* __restrict__ g,
                                               const int* __restrict__ cnt,
                                               const int* __restrict__ colpad,
                                               const float* __restrict__ dinv,
                                               const float* __restrict__ bias,
                                               _Float16* __restrict__ out, int N) {
  int node = blockIdx.x * 4 + (threadIdx.x >> 6);
  if (node >= N) return;
  const int lane = threadIdx.x & 63;
  const int es = lane >> 4;   // edge slot 0..3
  const int ch = lane & 15;   // 16-byte chunk 0..15
  const int deg = cnt[node];
  const int* __restrict__ row = colpad + (size_t)node * 64;

  float acc[8] = {0.f, 0.f, 0.f, 0.f, 0.f, 0.f, 0.f, 0.f};
  int e0 = 0;
  for (; e0 + 16 <= deg; e0 += 16) {
    int i0 = row[e0 + es];
    int i1 = row[e0 + 4 + es];
    int i2 = row[e0 + 8 + es];
    int i3 = row[e0 + 12 + es];
    half8 v0 = *(const half8*)(g + (size_t)i0 * HID + ch * 8);
    half8 v1 = *(const half8*)(g + (size_t)i1 * HID + ch * 8);
    half8 v2 = *(const half8*)(g + (size_t)i2 * HID + ch * 8);
    half8 v3 = *(const half8*)(g + (size_t)i3 * HID + ch * 8);
#pragma unroll
    for (int j = 0; j < 8; ++j)
      acc[j] += ((float)v0[j] + (float)v1[j]) + ((float)v2[j] + (float)v3[j]);
  }
  for (; e0 + 4 <= deg; e0 += 4) {
    int i0 = row[e0 + es];
    half8 v0 = *(const half8*)(g + (size_t)i0 * HID + ch * 8);
#pragma unroll
    for (int j = 0; j < 8; ++j) acc[j] += (float)v0[j];
  }
  const int rem = deg - e0;   // 0..3
  float selfw = 1.0f;
  if (rem > 0) {
    int i0 = (es < rem) ? row[e0 + es] : node;  // pad slots gather the self row
    half8 v0 = *(const half8*)(g + (size_t)i0 * HID + ch * 8);
#pragma unroll
    for (int j = 0; j < 8; ++j) acc[j] += (float)v0[j];
    selfw = 1.0f - (float)(4 - rem);  // compensate the (4-rem) extra self rows
  }

#pragma unroll
  for (int j = 0; j < 8; ++j) {
    acc[j] += __shfl_xor(acc[j], 16, 64);
    acc[j] += __shfl_xor(acc[j], 32, 64);
  }

  if (lane < 16) {
    half8 sv = *(const half8*)(g + (size_t)node * HID + ch * 8);
    const float di = dinv[node];
    half8 o;
#pragma unroll
    for (int j = 0; j < 8; ++j) {
      float v = di * (acc[j] + selfw * (float)sv[j]) + bias[ch * 8 + j];
      o[j] = (_Float16)fmaxf(v, 0.f);
    }
    *(half8*)(out + (size_t)node * HID + ch * 8) = o;
  }
}

// ---------------- final GEMM (MFMA): logits[N][40] = h[N][128] @ Wl[40][128]^T + bl ----------------

__global__ __launch_bounds__(256) void gemm40_mfma(const _Float16* __restrict__ h,
                                                   const float* __restrict__ Wl,
                                                   const float* __restrict__ bl,
                                                   float* __restrict__ out, int N) {
  __shared__ __align__(16) _Float16 wlds[48][136];

  const int tid = threadIdx.x;
  const int lane = tid & 63;
  const int wave = tid >> 6;
  const int row0 = blockIdx.x * 128;

#pragma unroll
  for (int i = 0; i < 6; ++i) {
    int idx4 = tid + i * 256;
    int c = idx4 >> 5;
    int ko = (idx4 & 31) * 4;
    float4 v = make_float4(0.f, 0.f, 0.f, 0.f);
    if (c < 40) v = *(const float4*)(Wl + (size_t)c * HID + ko);
    half4v hv;
    hv[0] = (_Float16)v.x; hv[1] = (_Float16)v.y;
    hv[2] = (_Float16)v.z; hv[3] = (_Float16)v.w;
    *(half4v*)&wlds[c][ko] = hv;
  }
  __syncthreads();

  f32x4 acc[2][3] = {};
  const int arow_in = lane & 15;
  const int kq = lane >> 4;

#pragma unroll
  for (int ks = 0; ks < 4; ++ks) {
    half8 a[2], b[3];
#pragma unroll
    for (int mi = 0; mi < 2; ++mi) {
      int gr = row0 + wave * 32 + mi * 16 + arow_in;
      if (gr >= N) gr = N - 1;
      a[mi] = *(const half8*)(h + (size_t)gr * HID + ks * 32 + kq * 8);
    }
#pragma unroll
    for (int ni = 0; ni < 3; ++ni) {
      int c = ni * 16 + arow_in;
      b[ni] = *(const half8*)&wlds[c][ks * 32 + kq * 8];
    }
#pragma unroll
    for (int mi = 0; mi < 2; ++mi)
#pragma unroll
      for (int ni = 0; ni < 3; ++ni)
        acc[mi][ni] = __builtin_amdgcn_mfma_f32_16x16x32_f16(a[mi], b[ni], acc[mi][ni], 0, 0, 0);
  }

  const int rsub = (lane >> 4) * 4;
#pragma unroll
  for (int ni = 0; ni < 3; ++ni) {
    int col = ni * 16 + (lane & 15);
    if (col >= 40) continue;
    float bv = bl[col];
#pragma unroll
    for (int mi = 0; mi < 2; ++mi) {
#pragma unroll
      for (int j = 0; j < 4; ++j) {
        int gr = row0 + wave * 32 + mi * 16 + rsub + j;
        if (gr < N) out[(size_t)gr * 40 + col] = acc[mi][ni][j] + bv;
      }
    }
  }
}

// ---------------- launch ----------------

extern "C" void kernel_launch(void* const* d_in, const int* in_sizes, int n_in,
                              void* d_out, int out_size, void* d_ws, size_t ws_size,
                              hipStream_t stream) {
  const float* x = (const float*)d_in[0];
  const int* ei = (const int*)d_in[1];
  const float* W0 = (const float*)d_in[2];
  const float* b0 = (const float*)d_in[3];
  const float* Wc = (const float*)d_in[4];
  const float* bc = (const float*)d_in[5];
  const float* Wl = (const float*)d_in[6];
  const float* bl = (const float*)d_in[7];
  float* out = (float*)d_out;

  const int N = in_sizes[0] / 512;
  const int E = in_sizes[1] / 2;
  const int NB = (N + (1 << BSHIFT) - 1) >> BSHIFT;  // 98 for N=100000

  char* ws = (char*)d_ws;
  size_t off = 0;
  auto alloc = [&](size_t bytes) -> char* {
    char* p = ws + off;
    off += (bytes + 511) & ~(size_t)511;
    return p;
  };
  float* dinv = (float*)alloc((size_t)N * 4);
  int* cnt = (int*)alloc((size_t)N * 4);
  int* gcur = (int*)alloc(128 * 4);
  int* colpad = (int*)alloc((size_t)N * 64 * 4);
  int2* bbuf = (int2*)alloc((size_t)NB * BCAP * 8);
  _Float16* hA = (_Float16*)alloc((size_t)N * HID * 2);
  _Float16* hB = (_Float16*)alloc((size_t)N * HID * 2);
  _Float16* hG = (_Float16*)alloc((size_t)N * HID * 2);
  _Float16* W0h = (_Float16*)alloc((size_t)HID * 512 * 2);
  _Float16* Wch = (_Float16*)alloc((size_t)3 * HID * HID * 2);

  const int nb_g = (N + 127) / 128;
  const int nb64 = (N + 63) / 64;

  zero_i32<<<1, 256, 0, stream>>>(gcur, 128);
  bin_edges<<<512, 256, 0, stream>>>(ei, gcur, bbuf, E, NB);
  scatter_pad<<<NB, 256, 0, stream>>>(bbuf, gcur, colpad, cnt, dinv, N);

  const int nw0 = HID * 512, nwc = 3 * HID * HID;
  cvt_w2<<<(nw0 + nwc + 255) / 256, 256, 0, stream>>>(W0, nw0, Wc, nwc, W0h, Wch);

  // input layer: hA = relu(x @ W0^T + b0)
  gemm512_panel<<<nb64, 512, 0, stream>>>(x, W0h, b0, hA, N);

  _Float16* bufs[2] = {hA, hB};
  int cur = 0;
  for (int l = 0; l < 3; ++l) {
    gemm128_panel<<<nb64, 512, 0, stream>>>(bufs[cur], Wch + (size_t)l * HID * HID,
                                            dinv, hG, N);
    agg_pad<<<(N + 3) / 4, 256, 0, stream>>>(hG, cnt, colpad, dinv, bc + (size_t)l * HID,
                                             bufs[1 - cur], N);
    cur = 1 - cur;
  }

  gemm40_mfma<<<nb_g, 256, 0, stream>>>(bufs[cur], Wl, bl, out, N);
}

// Round 19
// 361.370 us; speedup vs baseline: 1.9534x; 1.0060x over previous
//
#include <hip/hip_runtime.h>

#define HID 128
#define BSHIFT 10            // 1024 dst-nodes per bucket
#define BCAP 20480           // bucket capacity (mean 16.3K, sigma ~127 -> 32 sigma)

typedef _Float16 half8 __attribute__((ext_vector_type(8)));
typedef _Float16 half4v __attribute__((ext_vector_type(4)));
typedef float f32x4 __attribute__((ext_vector_type(4)));

__device__ __forceinline__ half8 cvt8(f32x4 f0, f32x4 f1) {
  half8 h;
  h[0] = (_Float16)f0[0]; h[1] = (_Float16)f0[1];
  h[2] = (_Float16)f0[2]; h[3] = (_Float16)f0[3];
  h[4] = (_Float16)f1[0]; h[5] = (_Float16)f1[1];
  h[6] = (_Float16)f1[2]; h[7] = (_Float16)f1[3];
  return h;
}

// async global->LDS, 16B per lane; LDS dest = wave-uniform base + lane*16
#define GLDS16(gp, lp)                                                        \
  __builtin_amdgcn_global_load_lds(                                           \
      (const __attribute__((address_space(1))) void*)(gp),                    \
      (__attribute__((address_space(3))) void*)(lp), 16, 0, 0)

// ---------------- graph build: two-pass binned scatter ----------------

__global__ __launch_bounds__(256) void zero_i32(int* __restrict__ p, int n) {
  int i = blockIdx.x * 256 + threadIdx.x;
  if (i < n) p[i] = 0;
}

__global__ __launch_bounds__(256) void bin_edges(const int* __restrict__ ei,
                                                 int* __restrict__ gcur,
                                                 int2* __restrict__ buf,
                                                 int E, int NB) {
  __shared__ int bcnt[128];
  __shared__ int bbase[128];
  const int tid = threadIdx.x;

  for (int chunk = blockIdx.x * 2048; chunk < E; chunk += gridDim.x * 2048) {
    if (tid < NB) bcnt[tid] = 0;
    __syncthreads();
    int s[8], d[8], slot[8], b[8];
#pragma unroll
    for (int j = 0; j < 8; ++j) {
      int e = chunk + tid + j * 256;
      if (e < E) {
        s[j] = ei[e];
        d[j] = ei[E + e];
        b[j] = d[j] >> BSHIFT;
        slot[j] = atomicAdd(&bcnt[b[j]], 1);
      } else {
        b[j] = -1;
      }
    }
    __syncthreads();
    if (tid < NB && bcnt[tid] > 0) bbase[tid] = atomicAdd(&gcur[tid], bcnt[tid]);
    __syncthreads();
#pragma unroll
    for (int j = 0; j < 8; ++j) {
      if (b[j] >= 0) {
        int pos = bbase[b[j]] + slot[j];
        if (pos < BCAP) buf[(size_t)b[j] * BCAP + pos] = make_int2(s[j], d[j]);
      }
    }
    __syncthreads();
  }
}

__global__ __launch_bounds__(256) void scatter_pad(const int2* __restrict__ buf,
                                                   const int* __restrict__ gcur,
                                                   int* __restrict__ colpad,
                                                   int* __restrict__ cnt,
                                                   float* __restrict__ dinv, int N) {
  __shared__ int lcnt[1 << BSHIFT];
  const int b = blockIdx.x;
  const int base = b << BSHIFT;
  const int tid = threadIdx.x;
  for (int i = tid; i < (1 << BSHIFT); i += 256) lcnt[i] = 0;
  __syncthreads();

  int ne = gcur[b];
  if (ne > BCAP) ne = BCAP;
  const int2* __restrict__ bb = buf + (size_t)b * BCAP;
  for (int i = tid; i < ne; i += 256) {
    int2 p = bb[i];
    int pos = atomicAdd(&lcnt[p.y - base], 1);
    if (pos < 64) colpad[(size_t)p.y * 64 + pos] = p.x;
  }
  __syncthreads();
  for (int i = tid; i < (1 << BSHIFT); i += 256) {
    int n = base + i;
    if (n < N) {
      int c = lcnt[i];
      cnt[n] = c;
      dinv[n] = rsqrtf((float)(c + 1));
    }
  }
}

// ---------------- weight convert fp32 -> f16 ----------------

__global__ __launch_bounds__(256) void cvt_w2(const float* __restrict__ a, int na,
                                              const float* __restrict__ b, int nb,
                                              _Float16* __restrict__ oa,
                                              _Float16* __restrict__ ob) {
  int i = blockIdx.x * 256 + threadIdx.x;
  if (i < na) oa[i] = (_Float16)a[i];
  else if (i < na + nb) ob[i - na] = (_Float16)b[i - na];
}

// ---------------- layer-0 GEMM: hA = relu(x[N][512] @ W0h[128][512]^T + b0) ----------------
// R18 structure with QUARTER A-panel: As 16KB (64 rows x 128 k) + Bs 16KB =
// 32KB LDS -> 5 blocks/CU (10 waves/SIMD, +67% resident waves vs R18's 3
// blocks).  Outer kk loop (4 iters) re-stages the A quarter (512B/row
// contiguous reads, 8 full cache lines per row).

__global__ __launch_bounds__(512) void gemm512_panel(const float* __restrict__ Af,
                                                     const _Float16* __restrict__ Wh,
                                                     const float* __restrict__ b0,
                                                     _Float16* __restrict__ out, int N) {
  __shared__ __align__(16) char As[64 * 128 * 2];    // 16KB f16, chunk-XOR swizzled
  __shared__ __align__(16) char Bs[128 * 64 * 2];    // 16KB (single 64-k chunk)

  const int tid = threadIdx.x;
  const int lane = tid & 63;
  const int wave = tid >> 6;
  const int wgrp = wave & 3;          // row-group (16 rows)
  const int coff = (wave >> 2) * 64;  // col half
  const int row0 = blockIdx.x * 64;

  f32x4 acc[4] = {};

  for (int kk = 0; kk < 4; ++kk) {
    // ---- stage A quarter-panel: 64 rows x 128 f32 (512B/row contiguous); cvt f16 ----
#pragma unroll
    for (int p = 0; p < 2; ++p) {
      int idx = p * 512 + tid;        // float8 index, 1024 total
      int r = idx >> 4;               // 16 float8 per row-quarter
      int j = idx & 15;               // chunk within row-quarter
      int grow = row0 + r; if (grow >= N) grow = N - 1;
      const float* src = Af + (size_t)grow * 512 + kk * 128 + j * 8;
      f32x4 f0 = *(const f32x4*)(src);
      f32x4 f1 = *(const f32x4*)(src + 4);
      *(half8*)(As + r * 256 + ((j ^ (r & 7)) << 4)) = cvt8(f0, f1);
    }

    for (int k8 = 0; k8 < 2; ++k8) {
      // stage B chunk (kk*2+k8) via glds: 128 rows x 64 f16; 16 rows/wave
#pragma unroll
      for (int i = 0; i < 2; ++i) {
        int r = wave * 16 + i * 8 + (lane >> 3);
        int csw = (lane & 7) ^ (r & 7);
        GLDS16(Wh + (size_t)r * 512 + (kk * 2 + k8) * 64 + csw * 8,
               Bs + (wave * 16 + i * 8) * 128);
      }
      __syncthreads();  // drains glds + A ds_writes

#pragma unroll
      for (int sub = 0; sub < 2; ++sub) {
        int r = wgrp * 16 + (lane & 15);
        int ja = k8 * 8 + sub * 4 + (lane >> 4);   // within [0,16)
        half8 a = *(const half8*)(As + r * 256 + ((ja ^ (r & 7)) << 4));
        int jb = sub * 4 + (lane >> 4);
#pragma unroll
        for (int ni = 0; ni < 4; ++ni) {
          int c = coff + ni * 16 + (lane & 15);
          half8 b = *(const half8*)(Bs + c * 128 + ((jb ^ (c & 7)) << 4));
          acc[ni] = __builtin_amdgcn_mfma_f32_16x16x32_f16(a, b, acc[ni], 0, 0, 0);
        }
      }
      __syncthreads();  // all waves done reading As/Bs before overwrite
    }
  }

  // epilogue: row = row0 + wgrp*16 + (lane>>4)*4 + j, col = coff + ni*16 + (lane&15)
  const int rsub = (lane >> 4) * 4;
#pragma unroll
  for (int j = 0; j < 4; ++j) {
    int grow = row0 + wgrp * 16 + rsub + j;
    if (grow < N) {
#pragma unroll
      for (int ni = 0; ni < 4; ++ni) {
        int c = coff + ni * 16 + (lane & 15);
        float v = acc[ni][j] + b0[c];
        out[(size_t)grow * HID + c] = (_Float16)fmaxf(v, 0.f);
      }
    }
  }
}

// ---------------- mid GEMM: g = dinv * (h[N][128] @ Wc[128][128]^T) ----------------
// Whole A-panel (16KB) + whole B (32KB) staged via glds once; ONE barrier; 48KB -> 3 blocks/CU.

__global__ __launch_bounds__(512) void gemm128_panel(const _Float16* __restrict__ Ah,
                                                     const _Float16* __restrict__ Wh,
                                                     const float* __restrict__ rowscale,
                                                     _Float16* __restrict__ out, int N) {
  __shared__ __align__(16) char As[64 * 128 * 2];   // 16KB
  __shared__ __align__(16) char Bs[128 * 128 * 2];  // 32KB

  const int tid = threadIdx.x;
  const int lane = tid & 63;
  const int wave = tid >> 6;
  const int wgrp = wave & 3;
  const int coff = (wave >> 2) * 64;
  const int row0 = blockIdx.x * 64;

  // A: 64 rows x 16 chunks; per wave-instr: 4 rows x 16 chunks; 2 instrs (8 rows/wave)
#pragma unroll
  for (int i = 0; i < 2; ++i) {
    int r = wave * 8 + i * 4 + (lane >> 4);
    int grow = row0 + r; if (grow >= N) grow = N - 1;
    int csw = (lane & 15) ^ (r & 7);
    GLDS16(Ah + (size_t)grow * 128 + csw * 8, As + (wave * 8 + i * 4) * 256);
  }
  // B: 128 rows x 16 chunks; 4 instrs (16 rows/wave)
#pragma unroll
  for (int i = 0; i < 4; ++i) {
    int r = wave * 16 + i * 4 + (lane >> 4);
    int csw = (lane & 15) ^ (r & 7);
    GLDS16(Wh + (size_t)r * 128 + csw * 8, Bs + (wave * 16 + i * 4) * 256);
  }
  __syncthreads();

  f32x4 acc[4] = {};
#pragma unroll
  for (int sub = 0; sub < 4; ++sub) {
    int r = wgrp * 16 + (lane & 15);
    int j = sub * 4 + (lane >> 4);
    half8 a = *(const half8*)(As + r * 256 + ((j ^ (r & 7)) << 4));
#pragma unroll
    for (int ni = 0; ni < 4; ++ni) {
      int c = coff + ni * 16 + (lane & 15);
      half8 b = *(const half8*)(Bs + c * 256 + ((j ^ (c & 7)) << 4));
      acc[ni] = __builtin_amdgcn_mfma_f32_16x16x32_f16(a, b, acc[ni], 0, 0, 0);
    }
  }

  const int rsub = (lane >> 4) * 4;
#pragma unroll
  for (int j = 0; j < 4; ++j) {
    int grow = row0 + wgrp * 16 + rsub + j;
    if (grow < N) {
      float rs = rowscale[grow];
#pragma unroll
      for (int ni = 0; ni < 4; ++ni) {
        int c = coff + ni * 16 + (lane & 15);
        out[(size_t)grow * HID + c] = (_Float16)(acc[ni][j] * rs);
      }
    }
  }
}

// ---------------- sparse aggregation: 4 rows per wave-instruction ----------------

__global__ __launch_bounds__(256) void agg_pad(const _Float16* __restrict__ g,
                                               const int* __restrict__ cnt,
                                               const int* __restrict__ colpad,
                                               const float* __restrict__ dinv,
                                               const float* __restrict__ bias,
                                               _Float16* __restrict__ out, int N) {
  int node = blockIdx.x * 4 + (threadIdx.x >> 6);
  if (node >= N) return;
  const int lane = threadIdx.x & 63;
  const int es = lane >> 4;   // edge slot 0..3
  const int ch = lane & 15;   // 16-byte chunk 0..15
  const int deg = cnt[node];
  const int* __restrict__ row = colpad + (size_t)node * 64;

  float acc[8] = {0.f, 0.f, 0.f, 0.f, 0.f, 0.f, 0.f, 0.f};
  int e0 = 0;
  for (; e0 + 16 <= deg; e0 += 16) {
    int i0 = row[e0 + es];
    int i1 = row[e0 + 4 + es];
    int i2 = row[e0 + 8 + es];
    int i3 = row[e0 + 12 + es];
    half8 v0 = *(const half8*)(g + (size_t)i0 * HID + ch * 8);
    half8 v1 = *(const half8*)(g + (size_t)i1 * HID + ch * 8);
    half8 v2 = *(const half8*)(g + (size_t)i2 * HID + ch * 8);
    half8 v3 = *(const half8*)(g + (size_t)i3 * HID + ch * 8);
#pragma unroll
    for (int j = 0; j < 8; ++j)
      acc[j] += ((float)v0[j] + (float)v1[j]) + ((float)v2[j] + (float)v3[j]);
  }
  for (; e0 + 4 <= deg; e0 += 4) {
    int i0 = row[e0 + es];
    half8 v0 = *(const half8*)(g + (size_t)i0 * HID + ch * 8);
#pragma unroll
    for (int j = 0; j < 8; ++j) acc[j] += (float)v0[j];
  }
  const int rem = deg - e0;   // 0..3
  float selfw = 1.0f;
  if (rem > 0) {
    int i0 = (es < rem) ? row[e0 + es] : node;  // pad slots gather the self row
    half8 v0 = *(const half8*)(g + (size_t)i0 * HID + ch * 8);
#pragma unroll
    for (int j = 0; j < 8; ++j) acc[j] += (float)v0[j];
    selfw = 1.0f - (float)(4 - rem);  // compensate the (4-rem) extra self rows
  }

#pragma unroll
  for (int j = 0; j < 8; ++j) {
    acc[j] += __shfl_xor(acc[j], 16, 64);
    acc[j] += __shfl_xor(acc[j], 32, 64);
  }

  if (lane < 16) {
    half8 sv = *(const half8*)(g + (size_t)node * HID + ch * 8);
    const float di = dinv[node];
    half8 o;
#pragma unroll
    for (int j = 0; j < 8; ++j) {
      float v = di * (acc[j] + selfw * (float)sv[j]) + bias[ch * 8 + j];
      o[j] = (_Float16)fmaxf(v, 0.f);
    }
    *(half8*)(out + (size_t)node * HID + ch * 8) = o;
  }
}

// ---------------- final GEMM (MFMA): logits[N][40] = h[N][128] @ Wl[40][128]^T + bl ----------------

__global__ __launch_bounds__(256) void gemm40_mfma(const _Float16* __restrict__ h,
                                                   const float* __restrict__ Wl,
                                                   const float* __restrict__ bl,
                                                   float* __restrict__ out, int N) {
  __shared__ __align__(16) _Float16 wlds[48][136];

  const int tid = threadIdx.x;
  const int lane = tid & 63;
  const int wave = tid >> 6;
  const int row0 = blockIdx.x * 128;

#pragma unroll
  for (int i = 0; i < 6; ++i) {
    int idx4 = tid + i * 256;
    int c = idx4 >> 5;
    int ko = (idx4 & 31) * 4;
    float4 v = make_float4(0.f, 0.f, 0.f, 0.f);
    if (c < 40) v = *(const float4*)(Wl + (size_t)c * HID + ko);
    half4v hv;
    hv[0] = (_Float16)v.x; hv[1] = (_Float16)v.y;
    hv[2] = (_Float16)v.z; hv[3] = (_Float16)v.w;
    *(half4v*)&wlds[c][ko] = hv;
  }
  __syncthreads();

  f32x4 acc[2][3] = {};
  const int arow_in = lane & 15;
  const int kq = lane >> 4;

#pragma unroll
  for (int ks = 0; ks < 4; ++ks) {
    half8 a[2], b[3];
#pragma unroll
    for (int mi = 0; mi < 2; ++mi) {
      int gr = row0 + wave * 32 + mi * 16 + arow_in;
      if (gr >= N) gr = N - 1;
      a[mi] = *(const half8*)(h + (size_t)gr * HID + ks * 32 + kq * 8);
    }
#pragma unroll
    for (int ni = 0; ni < 3; ++ni) {
      int c = ni * 16 + arow_in;
      b[ni] = *(const half8*)&wlds[c][ks * 32 + kq * 8];
    }
#pragma unroll
    for (int mi = 0; mi < 2; ++mi)
#pragma unroll
      for (int ni = 0; ni < 3; ++ni)
        acc[mi][ni] = __builtin_amdgcn_mfma_f32_16x16x32_f16(a[mi], b[ni], acc[mi][ni], 0, 0, 0);
  }

  const int rsub = (lane >> 4) * 4;
#pragma unroll
  for (int ni = 0; ni < 3; ++ni) {
    int col = ni * 16 + (lane & 15);
    if (col >= 40) continue;
    float bv = bl[col];
#pragma unroll
    for (int mi = 0; mi < 2; ++mi) {
#pragma unroll
      for (int j = 0; j < 4; ++j) {
        int gr = row0 + wave * 32 + mi * 16 + rsub + j;
        if (gr < N) out[(size_t)gr * 40 + col] = acc[mi][ni][j] + bv;
      }
    }
  }
}

// ---------------- launch ----------------

extern "C" void kernel_launch(void* const* d_in, const int* in_sizes, int n_in,
                              void* d_out, int out_size, void* d_ws, size_t ws_size,
                              hipStream_t stream) {
  const float* x = (const float*)d_in[0];
  const int* ei = (const int*)d_in[1];
  const float* W0 = (const float*)d_in[2];
  const float* b0 = (const float*)d_in[3];
  const float* Wc = (const float*)d_in[4];
  const float* bc = (const float*)d_in[5];
  const float* Wl = (const float*)d_in[6];
  const float* bl = (const float*)d_in[7];
  float* out = (float*)d_out;

  const int N = in_sizes[0] / 512;
  const int E = in_sizes[1] / 2;
  const int NB = (N + (1 << BSHIFT) - 1) >> BSHIFT;  // 98 for N=100000

  char* ws = (char*)d_ws;
  size_t off = 0;
  auto alloc = [&](size_t bytes) -> char* {
    char* p = ws + off;
    off += (bytes + 511) & ~(size_t)511;
    return p;
  };
  float* dinv = (float*)alloc((size_t)N * 4);
  int* cnt = (int*)alloc((size_t)N * 4);
  int* gcur = (int*)alloc(128 * 4);
  int* colpad = (int*)alloc((size_t)N * 64 * 4);
  int2* bbuf = (int2*)alloc((size_t)NB * BCAP * 8);
  _Float16* hA = (_Float16*)alloc((size_t)N * HID * 2);
  _Float16* hB = (_Float16*)alloc((size_t)N * HID * 2);
  _Float16* hG = (_Float16*)alloc((size_t)N * HID * 2);
  _Float16* W0h = (_Float16*)alloc((size_t)HID * 512 * 2);
  _Float16* Wch = (_Float16*)alloc((size_t)3 * HID * HID * 2);

  const int nb_g = (N + 127) / 128;
  const int nb64 = (N + 63) / 64;

  zero_i32<<<1, 256, 0, stream>>>(gcur, 128);
  bin_edges<<<512, 256, 0, stream>>>(ei, gcur, bbuf, E, NB);
  scatter_pad<<<NB, 256, 0, stream>>>(bbuf, gcur, colpad, cnt, dinv, N);

  const int nw0 = HID * 512, nwc = 3 * HID * HID;
  cvt_w2<<<(nw0 + nwc + 255) / 256, 256, 0, stream>>>(W0, nw0, Wc, nwc, W0h, Wch);

  // input layer: hA = relu(x @ W0^T + b0)
  gemm512_panel<<<nb64, 512, 0, stream>>>(x, W0h, b0, hA, N);

  _Float16* bufs[2] = {hA, hB};
  int cur = 0;
  for (int l = 0; l < 3; ++l) {
    gemm128_panel<<<nb64, 512, 0, stream>>>(bufs[cur], Wch + (size_t)l * HID * HID,
                                            dinv, hG, N);
    agg_pad<<<(N + 3) / 4, 256, 0, stream>>>(hG, cnt, colpad, dinv, bc + (size_t)l * HID,
                                             bufs[1 - cur], N);
    cur = 1 - cur;
  }

  gemm40_mfma<<<nb_g, 256, 0, stream>>>(bufs[cur], Wl, bl, out, N);
}